// Round 18
// baseline (299.229 us; speedup 1.0000x reference)
//
#include <hip/hip_runtime.h>

typedef unsigned short u16;
typedef unsigned int   u32;
typedef __bf16 bf16;
typedef bf16  bf16x8 __attribute__((ext_vector_type(8)));
typedef float f32x4  __attribute__((ext_vector_type(4)));

__device__ __forceinline__ u16 bf16u(float f) {
    u32 x = __builtin_bit_cast(u32, f);
    x += 0x7fffu + ((x >> 16) & 1u);   // RNE
    return (u16)(x >> 16);
}

__device__ __forceinline__ void gl_lds16(const void* g, void* l) {
    __builtin_amdgcn_global_load_lds(
        (const __attribute__((address_space(1))) u32*)g,
        (__attribute__((address_space(3))) u32*)l, 16, 0, 0);
}

// ---- merged prep: fp32->bf16 convert (z==4) + 4 weight transposes (z<4) ----
__global__ __launch_bounds__(256) void prep_all(
    const float* __restrict__ hidden, ushort4* __restrict__ Xb,
    const float* __restrict__ Wq, const float* __restrict__ Wk,
    const float* __restrict__ Wv, const float* __restrict__ Wo,
    u16* __restrict__ WqkvT, u16* __restrict__ WoT)
{
    const int z = blockIdx.z;
    if (z == 4) {   // cvt: 2048 blocks x 8 float4-chunks of 256
        const float4* in = (const float4*)hidden;
        int b = blockIdx.y * 32 + blockIdx.x;
#pragma unroll
        for (int it = 0; it < 8; it++) {
            int i = (b << 11) + (it << 8) + threadIdx.x;
            float4 f = in[i];
            ushort4 o;
            o.x = bf16u(f.x); o.y = bf16u(f.y); o.z = bf16u(f.z); o.w = bf16u(f.w);
            Xb[i] = o;
        }
        return;
    }
    const float* W; u16* WT; int rows, cols;
    if (z < 3) {
        if (blockIdx.y >= 32) return;
        W = (z == 0) ? Wq : (z == 1) ? Wk : Wv;
        WT = WqkvT + (size_t)z * 1024 * 1024;
        rows = 1024; cols = 1024;
    } else {
        W = Wo; WT = WoT; rows = 2048; cols = 1024;
    }
    __shared__ float t[32][33];
    int bx = blockIdx.x * 32, by = blockIdx.y * 32;
    int x = threadIdx.x & 31, y = threadIdx.x >> 5;
#pragma unroll
    for (int i = 0; i < 32; i += 8)
        t[y + i][x] = W[(size_t)(by + y + i) * cols + bx + x];
    __syncthreads();
#pragma unroll
    for (int i = 0; i < 32; i += 8)
        WT[(size_t)(bx + y + i) * rows + by + x] = bf16u(t[x][y + i]);
}

#define BAR   __builtin_amdgcn_s_barrier()
#define SB0   __builtin_amdgcn_sched_barrier(0)
#define VM6   asm volatile("s_waitcnt vmcnt(6)" ::: "memory")
#define VM4   asm volatile("s_waitcnt vmcnt(4)" ::: "memory")
#define VM0   asm volatile("s_waitcnt vmcnt(0)" ::: "memory")

// 2D XCD chunking with separate m/n shifts: XCD x owns (m-quarter, n-half).
// Per-XCD B working set < 4 MB L2 -> B L2-resident; A read <=2x from HBM.
// Bijective: requires nx%2==0, ny%4==0 (all grids here satisfy).
#define XCD2D2(SHM, SHN) \
    const int nx = gridDim.x, ny = gridDim.y; \
    const int orig = blockIdx.y * nx + blockIdx.x; \
    const int xcd = orig & 7, idx = orig >> 3; \
    const int nxh = nx >> 1; \
    const int m0 = ((xcd >> 1) * (ny >> 2) + idx / nxh) << (SHM); \
    const int n0 = ((xcd & 1) * nxh + idx % nxh) << (SHN);

// ====== 128x256 GEMM, wide-N wave tile (r17, measured 133.3us QKV) ======
// 256 thr = 4 waves (2M x 2N), wave tile 64x128; BK=32; 3 bufs x 24 KB;
// 2 blocks/CU; single stage-point fat rotation, VM6 publish. Details: r17 hdr.
__global__ __launch_bounds__(256, 2) void gemm_wn(
    const u16* __restrict__ A, const u16* __restrict__ BT, void* __restrict__ Cout,
    const float* __restrict__ cosp, const float* __restrict__ sinp,
    int M, int N, int K, int mode)
{
    __shared__ u16 Ld[3][12288];   // per buf: A @0 (4096 u16), B @4096 (8192 u16)
    const int tid = threadIdx.x;
    const int wid = tid >> 6, lane = tid & 63;
    XCD2D2(7, 8)
    const int wr = wid >> 1, wc = wid & 1;

    const int srow = tid >> 2;                       // 0..63
    const int sg = (tid & 3) ^ ((srow >> 1) & 3);    // inverse-swizzled k-chunk
    const u16* aS = A + (size_t)(m0 + srow) * K + (sg << 3);
    const u16* bS = BT + (size_t)(n0 + srow) * K + (sg << 3);
    const size_t h64K = (size_t)64 * K;
    const int wdb = wid << 9;                        // wave-uniform dest (u16)
    const int nt = K >> 5;

#define STAGE(T, B_) do { if ((T) < nt) { const size_t _ko = (size_t)(T) << 5; \
        gl_lds16(aS + _ko,            &Ld[B_][wdb]); \
        gl_lds16(aS + _ko + h64K,     &Ld[B_][2048 + wdb]); \
        gl_lds16(bS + _ko,            &Ld[B_][4096 + wdb]); \
        gl_lds16(bS + _ko + h64K,     &Ld[B_][6144 + wdb]); \
        gl_lds16(bS + _ko + 2 * h64K, &Ld[B_][8192 + wdb]); \
        gl_lds16(bS + _ko + 3 * h64K, &Ld[B_][10240 + wdb]); } } while (0)

    const int phys = ((lane >> 4) ^ ((lane >> 1) & 3)) << 3;
    const int raw = ((wr << 6) + (lane & 15)) << 5;            // A row base
    const int rbw = 4096 + (((wc << 7) + (lane & 15)) << 5);   // B row base

    f32x4 acc[4][8] = {};

    STAGE(0, 0); STAGE(1, 1);
    VM6;                       // tile 0 landed; tile 1 (6 loads) in flight
    BAR; SB0;

    int b = 0, bs = 2;
    for (int t = 0; t < nt; ++t) {
        const u16* Lb = &Ld[b][0];
        bf16x8 fa[4], fb[8];
#pragma unroll
        for (int ni = 0; ni < 8; ni++)
            fb[ni] = *(const bf16x8*)&Lb[rbw + (ni << 9) + phys];
#pragma unroll
        for (int mi = 0; mi < 4; mi++)
            fa[mi] = *(const bf16x8*)&Lb[raw + (mi << 9) + phys];
        STAGE(t + 2, bs);
        BAR;
        __builtin_amdgcn_s_setprio(1);
#pragma unroll
        for (int mi = 0; mi < 4; mi++)
#pragma unroll
            for (int ni = 0; ni < 8; ni++)
                acc[mi][ni] = __builtin_amdgcn_mfma_f32_16x16x32_bf16(
                    fa[mi], fb[ni], acc[mi][ni], 0, 0, 0);
        __builtin_amdgcn_s_setprio(0);
        if (t + 2 < nt) { VM6; } else { VM0; }   // publish tile t+1
        BAR; SB0;
        b = (b == 2) ? 0 : b + 1;
        bs = (bs == 2) ? 0 : bs + 1;
    }
#undef STAGE

    const int colbase = n0 + (wc << 7) + (lane & 15);
    if (mode == 2) {
        float* C = (float*)Cout;
#pragma unroll
        for (int mi = 0; mi < 4; mi++)
#pragma unroll
            for (int r = 0; r < 4; r++) {
                int m = m0 + (wr << 6) + (mi << 4) + ((lane >> 4) << 2) + r;
                float* row = C + (size_t)m * N + colbase;
#pragma unroll
                for (int ni = 0; ni < 8; ni++) row[ni << 4] = acc[mi][ni][r];
            }
    } else if (n0 < 2048) {                   // fused QKV: RoPE region (Q and K)
        u16* C = (u16*)Cout;
#pragma unroll
        for (int mi = 0; mi < 4; mi++)
#pragma unroll
            for (int r = 0; r < 4; r++) {
                int m = m0 + (wr << 6) + (mi << 4) + ((lane >> 4) << 2) + r;
                const float* cb = cosp + ((size_t)m << 6);
                const float* sb = sinp + ((size_t)m << 6);
                u16* row = C + (size_t)m * N + colbase;
#pragma unroll
                for (int ni = 0; ni < 8; ni++) {
                    int d = ((ni & 3) << 4) + (lane & 15); // head-dim pos 0..63
                    float c = cb[d], s = sb[d];
                    float v0 = acc[mi][ni][r];
                    float vr = acc[mi][ni ^ 2][r];         // d +/- 32, same head
                    float o = fmaf(v0, c, ((ni & 3) < 2 ? -vr : vr) * s);
                    row[ni << 4] = bf16u(o);
                }
            }
    } else {                                  // V region: plain bf16
        u16* C = (u16*)Cout;
#pragma unroll
        for (int mi = 0; mi < 4; mi++)
#pragma unroll
            for (int r = 0; r < 4; r++) {
                int m = m0 + (wr << 6) + (mi << 4) + ((lane >> 4) << 2) + r;
                u16* row = C + (size_t)m * N + colbase;
#pragma unroll
                for (int ni = 0; ni < 8; ni++) row[ni << 4] = bf16u(acc[mi][ni][r]);
            }
    }
}

// ====== 256x256 GEMM, fat-phase 3-buffer (r16 Wo, measured ~91us) ======
__global__ __launch_bounds__(512, 2) void gemm_fat(
    const u16* __restrict__ A, const u16* __restrict__ BT, void* __restrict__ Cout,
    const float* __restrict__ cosp, const float* __restrict__ sinp,
    int M, int N, int K, int mode)
{
    __shared__ u16 Ld[3][16384];   // per buf: A @0 (8192 u16), B @8192
    const int tid = threadIdx.x;
    const int wid = tid >> 6, lane = tid & 63;
    XCD2D2(8, 8)
    const int wr = wid >> 2, wc = wid & 3;

    const int srow = tid >> 2;                     // row 0..127
    const int sl = (tid & 3) ^ ((srow >> 1) & 3);  // inverse-swizzled chunk
    const u16* aS0 = A + (size_t)(m0 + srow) * K + (sl << 3);
    const u16* aS1 = aS0 + (size_t)128 * K;
    const u16* bS0 = BT + (size_t)(n0 + srow) * K + (sl << 3);
    const u16* bS1 = bS0 + (size_t)128 * K;
    const int wdb = wid << 9;                      // wave-uniform dest (u16)
    const int nt = K >> 5;

#define STAGE(T, B_) do { if ((T) < nt) { size_t _ko = (size_t)(T) << 5; \
        gl_lds16(aS0 + _ko, &Ld[B_][wdb]); \
        gl_lds16(aS1 + _ko, &Ld[B_][4096 + wdb]); \
        gl_lds16(bS0 + _ko, &Ld[B_][8192 + wdb]); \
        gl_lds16(bS1 + _ko, &Ld[B_][12288 + wdb]); } } while (0)

    const int phys = ((lane >> 4) ^ ((lane >> 1) & 3)) << 3;   // u16 offset
    const int raw = ((wr << 7) + (lane & 15)) << 5;            // A row base (u16)
    const int rbw = (((wc << 6) + (lane & 15)) << 5) + 8192;   // B row base (u16)

    f32x4 acc[8][4] = {};

    STAGE(0, 0); STAGE(1, 1);
    VM4;                       // tile 0 landed; tile 1 (4 loads) in flight
    BAR; SB0;

    int b = 0, bs = 2;
    for (int t = 0; t < nt; ++t) {
        const u16* Lb = &Ld[b][0];
        bf16x8 fa[8], fb[4];
#pragma unroll
        for (int ni = 0; ni < 4; ni++)
            fb[ni] = *(const bf16x8*)&Lb[rbw + (ni << 9) + phys];
#pragma unroll
        for (int mi = 0; mi < 8; mi++)
            fa[mi] = *(const bf16x8*)&Lb[raw + (mi << 9) + phys];
        STAGE(t + 2, bs);
        BAR;
        __builtin_amdgcn_s_setprio(1);
#pragma unroll
        for (int mi = 0; mi < 8; mi++)
#pragma unroll
            for (int ni = 0; ni < 4; ni++)
                acc[mi][ni] = __builtin_amdgcn_mfma_f32_16x16x32_bf16(
                    fa[mi], fb[ni], acc[mi][ni], 0, 0, 0);
        __builtin_amdgcn_s_setprio(0);
        if (t + 2 < nt) { VM4; } else { VM0; }   // publish tile t+1
        BAR; SB0;
        b = (b == 2) ? 0 : b + 1;
        bs = (bs == 2) ? 0 : bs + 1;
    }
#undef STAGE

    const int colbase = n0 + (wc << 6) + (lane & 15);
    if (mode == 2) {
        float* C = (float*)Cout;
#pragma unroll
        for (int mi = 0; mi < 8; mi++)
#pragma unroll
            for (int r = 0; r < 4; r++) {
                int m = m0 + (wr << 7) + (mi << 4) + ((lane >> 4) << 2) + r;
                float* row = C + (size_t)m * N + colbase;
#pragma unroll
                for (int ni = 0; ni < 4; ni++) row[ni << 4] = acc[mi][ni][r];
            }
    } else if (n0 < 2048) {                   // fused QKV: RoPE region (Q and K)
        u16* C = (u16*)Cout;
#pragma unroll
        for (int mi = 0; mi < 8; mi++)
#pragma unroll
            for (int r = 0; r < 4; r++) {
                int m = m0 + (wr << 7) + (mi << 4) + ((lane >> 4) << 2) + r;
                const float* cb = cosp + ((size_t)m << 6);
                const float* sb = sinp + ((size_t)m << 6);
                u16* row = C + (size_t)m * N + colbase;
#pragma unroll
                for (int ni = 0; ni < 4; ni++) {
                    int d = (ni << 4) + (lane & 15);   // head-dim pos (0..63)
                    float c = cb[d], s = sb[d];
                    float v0 = acc[mi][ni][r];
                    float vr = acc[mi][ni ^ 2][r];     // d +/- 32 partner
                    float o = fmaf(v0, c, (ni < 2 ? -vr : vr) * s);
                    row[ni << 4] = bf16u(o);
                }
            }
    } else {                                  // V region: plain bf16
        u16* C = (u16*)Cout;
#pragma unroll
        for (int mi = 0; mi < 8; mi++)
#pragma unroll
            for (int r = 0; r < 4; r++) {
                int m = m0 + (wr << 7) + (mi << 4) + ((lane >> 4) << 2) + r;
                u16* row = C + (size_t)m * N + colbase;
#pragma unroll
                for (int ni = 0; ni < 4; ni++) row[ni << 4] = bf16u(acc[mi][ni][r]);
            }
    }
}

// ------- axial attention, 48KB LDS (Pl overlays dead Kl), 3 blocks/CU ------
__global__ __launch_bounds__(256) void axial_attn(
    const u16* __restrict__ qkv, const float* __restrict__ mask,
    u16* __restrict__ cat)
{
    __shared__ u16 sh[24576];       // 48 KB
    const int hmode = blockIdx.x >> 11;
    const int o2 = blockIdx.x & 2047;
    const int b = (o2 & 7) * 256 + (o2 >> 3);   // per-half XCD chunk swizzle
    const int a = b >> 4, hd = b & 15;
    const int tid = threadIdx.x, wid = tid >> 6, lane = tid & 63;
    const int tmul = hmode ? 128 : 1;
    const int tadd = hmode ? a : (a << 7);
    const size_t hoff = (size_t)hd << 6;

#pragma unroll
    for (int c = 0; c < 4; c++) {
        int row = (wid << 5) + (c << 3) + (lane >> 3);
        int sc = (lane & 7) ^ (row & 7);
        gl_lds16(qkv + (size_t)(row * tmul + tadd) * 3072 + 1024 + hoff + (sc << 3),
                 &sh[((wid << 5) + (c << 3)) << 6]);
    }
#pragma unroll
    for (int i = 0; i < 2; i++) {
        int pid = tid + (i << 8);          // 0..511
        int j0 = (pid >> 3) << 1, j1 = j0 | 1;
        int d0 = (pid & 7) << 3;
        uint4 r0 = *(const uint4*)(qkv + (size_t)(j0 * tmul + tadd) * 3072 + 2048 + hoff + d0);
        uint4 r1 = *(const uint4*)(qkv + (size_t)(j1 * tmul + tadd) * 3072 + 2048 + hoff + d0);
        const u16* e0 = (const u16*)&r0;
        const u16* e1 = (const u16*)&r1;
        int g = j0 >> 3, lo = j0 & 7;      // j0 even: lo even -> 4B aligned
#pragma unroll
        for (int t = 0; t < 8; t++) {
            int d = d0 + t;
            *(u32*)&sh[8192 + (d << 7) + ((g ^ (d & 15)) << 3) + lo] =
                (u32)e0[t] | ((u32)e1[t] << 16);
        }
    }
    bf16x8 aq[2][2];
#pragma unroll
    for (int qt = 0; qt < 2; qt++)
#pragma unroll
        for (int ks = 0; ks < 2; ks++) {
            int row = (wid << 5) + (qt << 4) + (lane & 15);
            aq[qt][ks] = *(const bf16x8*)(qkv + (size_t)(row * tmul + tadd) * 3072 + hoff
                                          + (ks << 5) + ((lane >> 4) << 3));
        }
    __syncthreads();

    f32x4 S[2][8] = {};
#pragma unroll
    for (int kt = 0; kt < 8; kt++) {
        bf16x8 bk[2];
#pragma unroll
        for (int ks = 0; ks < 2; ks++) {
            int row = (kt << 4) + (lane & 15);
            int ch = ((ks << 2) + (lane >> 4)) ^ (row & 7);
            bk[ks] = *(const bf16x8*)&sh[(row << 6) + (ch << 3)];
        }
#pragma unroll
        for (int qt = 0; qt < 2; qt++) {
            S[qt][kt] = __builtin_amdgcn_mfma_f32_16x16x32_bf16(aq[qt][0], bk[0], S[qt][kt], 0, 0, 0);
            S[qt][kt] = __builtin_amdgcn_mfma_f32_16x16x32_bf16(aq[qt][1], bk[1], S[qt][kt], 0, 0, 0);
        }
    }
    __syncthreads();   // all Kl reads done: sh[0..8191] is now free for Pl

    const float scale = 0.03125f;   // 1/sqrt(1024)
#pragma unroll
    for (int qt = 0; qt < 2; qt++) {
#pragma unroll
        for (int r = 0; r < 4; r++) {
            int qrow = (wid << 5) + (qt << 4) + ((lane >> 4) << 2) + r;
            const int plb = (qrow << 7) + ((qrow & 64) ? 8192 : 0);
            const float* mrow = mask + (hmode ? (a << 7) : (qrow << 7));
            float mx = -1e30f;
#pragma unroll
            for (int kt = 0; kt < 8; kt++) {
                float sv = fmaf(S[qt][kt][r], scale, mrow[(kt << 4) + (lane & 15)]);
                S[qt][kt][r] = sv;
                mx = fmaxf(mx, sv);
            }
            mx = fmaxf(mx, __shfl_xor(mx, 1));
            mx = fmaxf(mx, __shfl_xor(mx, 2));
            mx = fmaxf(mx, __shfl_xor(mx, 4));
            mx = fmaxf(mx, __shfl_xor(mx, 8));
            float sum = 0.f;
#pragma unroll
            for (int kt = 0; kt < 8; kt++) {
                float p = __expf(S[qt][kt][r] - mx);
                S[qt][kt][r] = p;
                sum += p;
            }
            sum += __shfl_xor(sum, 1);
            sum += __shfl_xor(sum, 2);
            sum += __shfl_xor(sum, 4);
            sum += __shfl_xor(sum, 8);
            float rinv = 1.0f / sum;
#pragma unroll
            for (int kt = 0; kt < 8; kt++) {
                int kcol = (kt << 4) + (lane & 15);
                int ch = (kcol >> 3) ^ (qrow & 15);
                sh[plb + (ch << 3) + (kcol & 7)] = bf16u(S[qt][kt][r] * rinv);
            }
        }
    }
    __syncthreads();

    f32x4 O[4][2] = {};
#pragma unroll
    for (int ks = 0; ks < 4; ks++) {
        bf16x8 av[4], bp[2];
#pragma unroll
        for (int qt = 0; qt < 2; qt++) {
            int qrow = (wid << 5) + (qt << 4) + (lane & 15);
            int ch = ((ks << 2) + (lane >> 4)) ^ (qrow & 15);
            bp[qt] = *(const bf16x8*)&sh[(qrow << 7) + ((qrow & 64) ? 8192 : 0) + (ch << 3)];
        }
#pragma unroll
        for (int dt = 0; dt < 4; dt++) {
            int drow = (dt << 4) + (lane & 15);
            int ch = ((ks << 2) + (lane >> 4)) ^ (drow & 15);
            av[dt] = *(const bf16x8*)&sh[8192 + (drow << 7) + (ch << 3)];
        }
#pragma unroll
        for (int dt = 0; dt < 4; dt++)
#pragma unroll
            for (int qt = 0; qt < 2; qt++)
                O[dt][qt] = __builtin_amdgcn_mfma_f32_16x16x32_bf16(av[dt], bp[qt], O[dt][qt], 0, 0, 0);
    }

    const int cbase = (hmode ? 1024 : 0) + (hd << 6);
#pragma unroll
    for (int dt = 0; dt < 4; dt++)
#pragma unroll
        for (int qt = 0; qt < 2; qt++) {
            int qrow = (wid << 5) + (qt << 4) + (lane & 15);
            int d0 = (dt << 4) + ((lane >> 4) << 2);
            size_t base = ((size_t)(qrow * tmul + tadd) << 11) + cbase + d0;
            ushort4 pk;
            pk.x = bf16u(O[dt][qt][0]);
            pk.y = bf16u(O[dt][qt][1]);
            pk.z = bf16u(O[dt][qt][2]);
            pk.w = bf16u(O[dt][qt][3]);
            *(ushort4*)(cat + base) = pk;
        }
}

extern "C" void kernel_launch(void* const* d_in, const int* in_sizes, int n_in,
                              void* d_out, int out_size, void* d_ws, size_t ws_size,
                              hipStream_t stream)
{
    (void)in_sizes; (void)n_in; (void)out_size; (void)ws_size;
    const float* hidden = (const float*)d_in[0];
    const float* mask   = (const float*)d_in[1];
    const float* cosp   = (const float*)d_in[2];
    const float* sinp   = (const float*)d_in[3];
    const float* Wq     = (const float*)d_in[4];
    const float* Wk     = (const float*)d_in[5];
    const float* Wv     = (const float*)d_in[6];
    const float* Wo     = (const float*)d_in[7];

    char* ws = (char*)d_ws;
    u16* Xb    = (u16*)(ws);                  // 33,554,432 B
    u16* WqkvT = (u16*)(ws + 33554432);       //  6,291,456 B
    u16* cat   = (u16*)(ws);                  // 67,108,864 B (reuse, stream-ordered)
    u16* WoT   = (u16*)(ws + 67108864);       //  4,194,304 B
    u16* qkvb  = (u16*)(ws + 71303168);       // 100,663,296 B

    prep_all<<<dim3(32, 64, 5), 256, 0, stream>>>(hidden, (ushort4*)Xb,
                                                  Wq, Wk, Wv, Wo, WqkvT, WoT);

    // fused QKV projection + RoPE: [16384,1024] x [1024,3072]  (wide-N, r17)
    gemm_wn<<<dim3(12, 128), 256, 0, stream>>>(Xb, WqkvT, qkvb, cosp, sinp, 16384, 3072, 1024, 1);

    axial_attn<<<4096, 256, 0, stream>>>(qkvb, mask, cat);

    // output projection: [16384,2048] x [2048,1024] -> fp32  (fat 256², r16)
    gemm_fat<<<dim3(4, 64), 512, 0, stream>>>(cat, WoT, d_out, nullptr, nullptr, 16384, 1024, 2048, 2);
}